// Round 5
// baseline (54.958 us; speedup 1.0000x reference)
//
#include <hip/hip_runtime.h>

// CategoryDense: out[b,c,o] = sum_i x[b,c,i] * kernel[c,i,o] + bias[c,o]
// B=8192, C=64, IN=64, OUT=64, fp32 in/out. bf16 MFMA, fp32 accum.
//
// Block = (category c, 256-batch tile), 4 waves. Swapped-operand MFMA:
// per 16x16 tile compute D' = kT_tile * xT_tile = (x*k)^T so each lane ends
// with 4 CONSECUTIVE output columns -> f32x4 stores.
// x staged in LDS as bf16 (32KB) via coalesced f32x4 loads + in-reg cvt +
// XOR-swizzled ds_write_b64 (16B-granule swizzle: seg16 ^= row&7), read back
// as conflict-free ds_read_b128 fragments. k staged bf16 linear (8KB).
// One barrier total. LDS 40KB -> 4 blocks/CU; VGPR<=128 -> 16 waves/CU.

constexpr int C_   = 64;
constexpr int IN_  = 64;
constexpr int OUT_ = 64;
constexpr int BT   = 256;

typedef __attribute__((ext_vector_type(8))) short bf16x8;
typedef __attribute__((ext_vector_type(4))) short s16x4;
typedef __attribute__((ext_vector_type(4))) float f32x4;

__device__ __forceinline__ short f2bf(float f) {
    union { float f; unsigned u; } v; v.f = f;
    unsigned r = v.u + 0x7FFF + ((v.u >> 16) & 1);   // RNE
    return (short)(r >> 16);
}

__global__ __launch_bounds__(256, 4)
void cat_dense_mfma2(const float* __restrict__ x,
                     const float* __restrict__ k,
                     const float* __restrict__ bias,
                     float* __restrict__ out) {
    __shared__ unsigned short xsb[BT * IN_];    // 32 KB bf16, swizzled
    __shared__ unsigned short ksb[IN_ * OUT_];  //  8 KB bf16, linear [i][o]

    const int tid  = threadIdx.x;
    const int wv   = tid >> 6;
    const int lane = tid & 63;
    const int c    = blockIdx.x & 63;
    const long bBase = (long)(blockIdx.x >> 6) * BT;

    const int lrow = lane & 15;   // D' col = batch row within 16-tile
    const int lkg  = lane >> 4;   // k-octet select; D' row-group

    // ---- stage k[c] -> bf16 LDS (linear). 1024 chunks of 4 f32, coalesced ----
    #pragma unroll
    for (int it = 0; it < 4; ++it) {
        int p = tid + it * 256;
        f32x4 v = *(const f32x4*)(k + (size_t)c * (IN_ * OUT_) + p * 4);
        s16x4 w;
        #pragma unroll
        for (int e = 0; e < 4; ++e) w[e] = f2bf(v[e]);
        *(s16x4*)(&ksb[p * 4]) = w;
    }

    // ---- stage x tile -> bf16 LDS (swizzled). 4096 chunks of 4 f32 ----
    // chunk q: row = q>>4, 8B-granule s8 = q&15; swizzle 16B granules by row&7.
    #pragma unroll
    for (int it = 0; it < 16; ++it) {
        int q   = tid + it * 256;
        int row = q >> 4, s8 = q & 15;
        f32x4 v = *(const f32x4*)(x + (size_t)(bBase + row) * (C_ * IN_)
                                    + c * IN_ + s8 * 4);
        s16x4 w;
        #pragma unroll
        for (int e = 0; e < 4; ++e) w[e] = f2bf(v[e]);
        int byteoff = row * 128 + ((((s8 >> 1) ^ (row & 7)) << 4) | ((s8 & 1) << 3));
        *(s16x4*)((char*)xsb + byteoff) = w;
    }

    // bias: lane's 4 consecutive output cols per nt
    f32x4 bv[4];
    #pragma unroll
    for (int nt = 0; nt < 4; ++nt)
        bv[nt] = *(const f32x4*)(bias + (size_t)c * OUT_ + nt * 16 + lkg * 4);

    __syncthreads();

    // ---- kT fragments (A-operand): A[row=o=lrow][k=i], one-time scalar reads ----
    bf16x8 kb[4][2];
    #pragma unroll
    for (int nt = 0; nt < 4; ++nt)
      #pragma unroll
      for (int ksi = 0; ksi < 2; ++ksi) {
        bf16x8 b;
        #pragma unroll
        for (int j = 0; j < 8; ++j)
            b[j] = (short)ksb[(ksi * 32 + lkg * 8 + j) * OUT_ + nt * 16 + lrow];
        kb[nt][ksi] = b;
      }

    // ---- two M=32 passes; xT fragments read per pass (conflict-free b128) ----
    #pragma unroll
    for (int p = 0; p < 2; ++p) {
        bf16x8 af[2][2];
        #pragma unroll
        for (int mt = 0; mt < 2; ++mt)
          #pragma unroll
          for (int ksi = 0; ksi < 2; ++ksi) {
            int row = wv * 64 + p * 32 + mt * 16 + lrow;
            int byteoff = row * 128 + ((((ksi * 4 + lkg)) ^ (row & 7)) << 4);
            af[mt][ksi] = *(const bf16x8*)((const char*)xsb + byteoff);
          }

        f32x4 acc[2][4];
        #pragma unroll
        for (int mt = 0; mt < 2; ++mt)
          #pragma unroll
          for (int nt = 0; nt < 4; ++nt)
            acc[mt][nt] = (f32x4){0.f, 0.f, 0.f, 0.f};

        #pragma unroll
        for (int ksi = 0; ksi < 2; ++ksi)
          #pragma unroll
          for (int mt = 0; mt < 2; ++mt)
            #pragma unroll
            for (int nt = 0; nt < 4; ++nt)
                acc[mt][nt] = __builtin_amdgcn_mfma_f32_16x16x32_bf16(
                                  kb[nt][ksi], af[mt][ksi], acc[mt][nt], 0, 0, 0);

        // D'[row=o'=lkg*4+reg][col=m'=lrow]: lane stores 4 consecutive out cols
        #pragma unroll
        for (int mt = 0; mt < 2; ++mt) {
            size_t rbase = (size_t)(bBase + wv * 64 + p * 32 + mt * 16 + lrow)
                               * (C_ * OUT_)
                         + (size_t)c * OUT_ + lkg * 4;
            #pragma unroll
            for (int nt = 0; nt < 4; ++nt) {
                f32x4 o = acc[mt][nt] + bv[nt];
                __builtin_nontemporal_store(o, (f32x4*)(out + rbase + nt * 16));
            }
        }
    }
}

extern "C" void kernel_launch(void* const* d_in, const int* in_sizes, int n_in,
                              void* d_out, int out_size, void* d_ws, size_t ws_size,
                              hipStream_t stream) {
    const float* x    = (const float*)d_in[0];
    const float* k    = (const float*)d_in[1];
    const float* bias = (const float*)d_in[2];
    float* out        = (float*)d_out;

    const int B     = in_sizes[0] / (C_ * IN_);   // 8192
    const int tiles = B / BT;                     // 32
    dim3 grid(64 * tiles);                        // c = blk & 63, tile = blk >> 6
    cat_dense_mfma2<<<grid, 256, 0, stream>>>(x, k, bias, out);
}

// Round 6
// 51.817 us; speedup vs baseline: 1.0606x; 1.0606x over previous
//
#include <hip/hip_runtime.h>

// CategoryDense: out[b,c,o] = sum_i x[b,c,i] * kernel[c,i,o] + bias[c,o]
// B=8192, C=64, IN=64, OUT=64, fp32 in/out. bf16 MFMA, fp32 accum.
//
// Block = (category c, 256-batch tile), 4 waves. Swapped-operand MFMA:
// per 16x16 tile compute D' = kT_tile * xT_tile = (x*k)^T so each lane ends
// with 4 CONSECUTIVE output columns -> f32x4 stores.
// x staged in LDS as bf16 (32KB) via coalesced f32x4 loads + in-reg cvt +
// XOR-swizzled ds_write_b64, read back as conflict-free ds_read_b128 frags.
// k staged bf16 linear (8KB). One barrier total.
// R6 change vs R5: PLAIN stores (no nontemporal) — nt hint caused ~41MB
// write amplification (172 vs 131MB; R1 plain stores measured exactly 131MB).

constexpr int C_   = 64;
constexpr int IN_  = 64;
constexpr int OUT_ = 64;
constexpr int BT   = 256;

typedef __attribute__((ext_vector_type(8))) short bf16x8;
typedef __attribute__((ext_vector_type(4))) short s16x4;
typedef __attribute__((ext_vector_type(4))) float f32x4;

__device__ __forceinline__ short f2bf(float f) {
    union { float f; unsigned u; } v; v.f = f;
    unsigned r = v.u + 0x7FFF + ((v.u >> 16) & 1);   // RNE
    return (short)(r >> 16);
}

__global__ __launch_bounds__(256, 4)
void cat_dense_mfma3(const float* __restrict__ x,
                     const float* __restrict__ k,
                     const float* __restrict__ bias,
                     float* __restrict__ out) {
    __shared__ unsigned short xsb[BT * IN_];    // 32 KB bf16, swizzled
    __shared__ unsigned short ksb[IN_ * OUT_];  //  8 KB bf16, linear [i][o]

    const int tid  = threadIdx.x;
    const int wv   = tid >> 6;
    const int lane = tid & 63;
    const int c    = blockIdx.x & 63;
    const long bBase = (long)(blockIdx.x >> 6) * BT;

    const int lrow = lane & 15;   // D' col = batch row within 16-tile
    const int lkg  = lane >> 4;   // k-octet select; D' row-group

    // ---- stage k[c] -> bf16 LDS (linear). 1024 chunks of 4 f32, coalesced ----
    #pragma unroll
    for (int it = 0; it < 4; ++it) {
        int p = tid + it * 256;
        f32x4 v = *(const f32x4*)(k + (size_t)c * (IN_ * OUT_) + p * 4);
        s16x4 w;
        #pragma unroll
        for (int e = 0; e < 4; ++e) w[e] = f2bf(v[e]);
        *(s16x4*)(&ksb[p * 4]) = w;
    }

    // ---- stage x tile -> bf16 LDS (swizzled). 4096 chunks of 4 f32 ----
    // chunk q: row = q>>4, 8B-granule s8 = q&15; swizzle 16B granules by row&7.
    #pragma unroll
    for (int it = 0; it < 16; ++it) {
        int q   = tid + it * 256;
        int row = q >> 4, s8 = q & 15;
        f32x4 v = *(const f32x4*)(x + (size_t)(bBase + row) * (C_ * IN_)
                                    + c * IN_ + s8 * 4);
        s16x4 w;
        #pragma unroll
        for (int e = 0; e < 4; ++e) w[e] = f2bf(v[e]);
        int byteoff = row * 128 + ((((s8 >> 1) ^ (row & 7)) << 4) | ((s8 & 1) << 3));
        *(s16x4*)((char*)xsb + byteoff) = w;
    }

    // bias: lane's 4 consecutive output cols per nt
    f32x4 bv[4];
    #pragma unroll
    for (int nt = 0; nt < 4; ++nt)
        bv[nt] = *(const f32x4*)(bias + (size_t)c * OUT_ + nt * 16 + lkg * 4);

    __syncthreads();

    // ---- kT fragments (A-operand): A[row=o=lrow][k=i], one-time scalar reads ----
    bf16x8 kb[4][2];
    #pragma unroll
    for (int nt = 0; nt < 4; ++nt)
      #pragma unroll
      for (int ksi = 0; ksi < 2; ++ksi) {
        bf16x8 b;
        #pragma unroll
        for (int j = 0; j < 8; ++j)
            b[j] = (short)ksb[(ksi * 32 + lkg * 8 + j) * OUT_ + nt * 16 + lrow];
        kb[nt][ksi] = b;
      }

    // ---- two M=32 passes; xT fragments read per pass (conflict-free b128) ----
    #pragma unroll
    for (int p = 0; p < 2; ++p) {
        bf16x8 af[2][2];
        #pragma unroll
        for (int mt = 0; mt < 2; ++mt)
          #pragma unroll
          for (int ksi = 0; ksi < 2; ++ksi) {
            int row = wv * 64 + p * 32 + mt * 16 + lrow;
            int byteoff = row * 128 + ((((ksi * 4 + lkg)) ^ (row & 7)) << 4);
            af[mt][ksi] = *(const bf16x8*)((const char*)xsb + byteoff);
          }

        f32x4 acc[2][4];
        #pragma unroll
        for (int mt = 0; mt < 2; ++mt)
          #pragma unroll
          for (int nt = 0; nt < 4; ++nt)
            acc[mt][nt] = (f32x4){0.f, 0.f, 0.f, 0.f};

        #pragma unroll
        for (int ksi = 0; ksi < 2; ++ksi)
          #pragma unroll
          for (int mt = 0; mt < 2; ++mt)
            #pragma unroll
            for (int nt = 0; nt < 4; ++nt)
                acc[mt][nt] = __builtin_amdgcn_mfma_f32_16x16x32_bf16(
                                  kb[nt][ksi], af[mt][ksi], acc[mt][nt], 0, 0, 0);

        // D'[row=o'][col=m'=lrow]: lane stores 4 consecutive out cols, plain f32x4
        #pragma unroll
        for (int mt = 0; mt < 2; ++mt) {
            size_t rbase = (size_t)(bBase + wv * 64 + p * 32 + mt * 16 + lrow)
                               * (C_ * OUT_)
                         + (size_t)c * OUT_ + lkg * 4;
            #pragma unroll
            for (int nt = 0; nt < 4; ++nt) {
                f32x4 o = acc[mt][nt] + bv[nt];
                *(f32x4*)(out + rbase + nt * 16) = o;
            }
        }
    }
}

extern "C" void kernel_launch(void* const* d_in, const int* in_sizes, int n_in,
                              void* d_out, int out_size, void* d_ws, size_t ws_size,
                              hipStream_t stream) {
    const float* x    = (const float*)d_in[0];
    const float* k    = (const float*)d_in[1];
    const float* bias = (const float*)d_in[2];
    float* out        = (float*)d_out;

    const int B     = in_sizes[0] / (C_ * IN_);   // 8192
    const int tiles = B / BT;                     // 32
    dim3 grid(64 * tiles);                        // c = blk & 63, tile = blk >> 6
    cat_dense_mfma3<<<grid, 256, 0, stream>>>(x, k, bias, out);
}